// Round 19
// baseline (84.829 us; speedup 1.0000x reference)
//
#include <hip/hip_runtime.h>

// MHA forward: x[8,1024,768] fp32; Wq/Wk/Wv[12,768,64] fp32 -> out[8,1024,768] fp32
// cvt x->f16, cvt W->f16T (LDS transpose), QKV proj (f16 MFMA, 128x192 tile, 3-buffer
// depth-2 global_load_lds pipeline, counted vmcnt, coalesced epilogue), flash attn
// (swapped-operand MFMA, dbuf + reg prefetch, 2 q-tiles/block DOUBLE-PIPELINED:
// QK(0,1) -> SM(0,1) -> PV(0) -> PV(1), P via per-wave LDS, deferred softmax).

#define Bq 8
#define Sq 1024
#define Dq 768
#define Hq 12
#define DHq 64

typedef _Float16 f16;
typedef f16 f16x8 __attribute__((ext_vector_type(8)));
typedef float f32x4 __attribute__((ext_vector_type(4)));

#define MFMA16(a, b, c) __builtin_amdgcn_mfma_f32_16x16x32_f16(a, b, c, 0, 0, 0)

// 0.125 (1/sqrt(64)) * log2(e): folded into Q so attn works in exp2 domain
#define QSCL 0.1803368801111244f

#if __has_builtin(__builtin_amdgcn_exp2f)
#define EXP2(x) __builtin_amdgcn_exp2f(x)
#else
#define EXP2(x) exp2f(x)
#endif

__device__ __forceinline__ void gload16(const f16* g, f16* l) {
  __builtin_amdgcn_global_load_lds(
      (const __attribute__((address_space(1))) void*)g,
      (__attribute__((address_space(3))) void*)l, 16, 0, 0);
}

// ---------- convert x (fp32 -> f16), 8 elems/thread ----------
__global__ __launch_bounds__(256) void cvt_x_kernel(const float* __restrict__ x,
                                                    f16* __restrict__ xh) {
  int i = blockIdx.x * 256 + threadIdx.x;
  const float4* src = reinterpret_cast<const float4*>(x) + i * 2;
  float4 a = src[0], b = src[1];
  f16x8 o;
  o[0] = (f16)a.x; o[1] = (f16)a.y; o[2] = (f16)a.z; o[3] = (f16)a.w;
  o[4] = (f16)b.x; o[5] = (f16)b.y; o[6] = (f16)b.z; o[7] = (f16)b.w;
  *reinterpret_cast<f16x8*>(xh + i * 8) = o;
}

// ---------- convert W -> WT f16 via LDS transpose, layout [w][h][e(64)][k(768)] ----------
__global__ __launch_bounds__(256) void cvt_w_kernel(const float* __restrict__ Wq,
                                                    const float* __restrict__ Wk,
                                                    const float* __restrict__ Wv,
                                                    f16* __restrict__ WT) {
  __shared__ float tile[64][65];
  const int kt = blockIdx.x, h = blockIdx.y, w = blockIdx.z;
  const float* W = (w == 0) ? Wq : (w == 1) ? Wk : Wv;
  const int t = threadIdx.x;
  const int c0 = t & 63, r4 = t >> 6;
#pragma unroll
  for (int i = 0; i < 16; i++) {
    int kr = i * 4 + r4;
    tile[kr][c0] = W[((size_t)h * Dq + kt * 64 + kr) * DHq + c0];
  }
  __syncthreads();
#pragma unroll
  for (int i = 0; i < 16; i++) {
    int e2 = i * 4 + r4;
    WT[((size_t)(w * Hq + h) * DHq + e2) * Dq + kt * 64 + c0] = (f16)tile[c0][e2];
  }
}

// ---------- QKV projection: 128x192 tile, BK=32, 3-buffer depth-2 pipeline ----------
__global__ __launch_bounds__(256) void proj_kernel(const f16* __restrict__ xh,
                                                   const f16* __restrict__ WT,
                                                   f16* __restrict__ Q,
                                                   f16* __restrict__ K,
                                                   f16* __restrict__ Vt) {
  __shared__ __align__(1024) f16 smem[30720];  // A 3x4096 @0, B 3x6144 @12288

  const int L = blockIdx.x;            // 0..767
  const int j = L >> 3;                // 0..95
  const int mt = (L & 7) + 8 * (j & 7);  // 0..63, mt%8 == L%8 (XCD-local x tiles)
  const int h = j >> 3;                // 0..11
  const int row0 = mt * 128;
  const int t = threadIdx.x;
  const int wv = t >> 6;
  const int lane = t & 63;
  const int g = lane >> 4;
  const int ql = lane & 15;
  const int wvm = wv >> 1, wvn = wv & 1;

  const int lr = lane >> 2;                          // row within 16-row chunk
  const int scg = (lane & 3) ^ ((lane >> 3) & 3);    // pre-swizzled source unit

  const f16* xsrc = xh + (size_t)row0 * Dq;
  const f16* wsrc = WT + (size_t)h * DHq * Dq;

  const f16* gA0 = xsrc + (size_t)(wv * 32 + lr) * Dq + scg * 8;
  const f16* gA1 = gA0 + (size_t)16 * Dq;
  const int n0 = wv * 48 + lr, n1 = n0 + 16, n2 = n0 + 32;
  const f16* gB0 = wsrc + ((size_t)(n0 >> 6) * Hq * DHq + (n0 & 63)) * Dq + scg * 8;
  const f16* gB1 = wsrc + ((size_t)(n1 >> 6) * Hq * DHq + (n1 & 63)) * Dq + scg * 8;
  const f16* gB2 = wsrc + ((size_t)(n2 >> 6) * Hq * DHq + (n2 & 63)) * Dq + scg * 8;

  f32x4 acc[4][6] = {};

#define PROJ_STAGE(buf)                                              \
  do {                                                               \
    f16* sA_ = smem + (buf) * 4096 + wv * 1024;                      \
    f16* sB_ = smem + 12288 + (buf) * 6144 + wv * 1536;              \
    gload16(gA0, sA_); gload16(gA1, sA_ + 512);                      \
    gload16(gB0, sB_); gload16(gB1, sB_ + 512);                      \
    gload16(gB2, sB_ + 1024);                                        \
    gA0 += 32; gA1 += 32; gB0 += 32; gB1 += 32; gB2 += 32;           \
  } while (0)

  PROJ_STAGE(0);
  PROJ_STAGE(1);

  const int rq = (g ^ ((ql >> 1) & 3)) * 8;  // swizzled read unit offset (elems)
  const f16* rA = smem + (wvm * 64 + ql) * 32 + rq;
  const f16* rB = smem + 12288 + (wvn * 96 + ql) * 32 + rq;

#pragma unroll
  for (int step = 0; step < 24; step++) {
    if (step < 23) asm volatile("s_waitcnt vmcnt(5) lgkmcnt(0)" ::: "memory");
    else           asm volatile("s_waitcnt vmcnt(0) lgkmcnt(0)" ::: "memory");
    __builtin_amdgcn_s_barrier();
    __builtin_amdgcn_sched_barrier(0);
    if (step < 22) PROJ_STAGE((step + 2) % 3);
    const int cur = step % 3;
    f16x8 af[4], bf[6];
#pragma unroll
    for (int mf = 0; mf < 4; mf++)
      af[mf] = *reinterpret_cast<const f16x8*>(rA + cur * 4096 + mf * 512);
#pragma unroll
    for (int nf = 0; nf < 6; nf++)
      bf[nf] = *reinterpret_cast<const f16x8*>(rB + cur * 6144 + nf * 512);
    __builtin_amdgcn_s_setprio(1);
#pragma unroll
    for (int mf = 0; mf < 4; mf++)
#pragma unroll
      for (int nf = 0; nf < 6; nf++)
        acc[mf][nf] = MFMA16(af[mf], bf[nf], acc[mf][nf]);
    __builtin_amdgcn_s_setprio(0);
  }
#undef PROJ_STAGE
  __syncthreads();  // all LDS reads done before smem reuse below

  const int b = row0 >> 10;
  const int s0 = row0 & 1023;
  const size_t base_sd = ((size_t)(b * Hq + h) * Sq) * DHq;

  // epilogue: stage Q [s][dh], K [s][dh], V [dh][s] in LDS, then coalesced stores.
  f16* tq = smem;            // [128][72]
  f16* tk = smem + 9216;     // [128][72]
  f16* vbuf = smem + 18432;  // [64][136]

#pragma unroll
  for (int nf = 0; nf < 6; nf++) {
    const int c = wvn * 96 + nf * 16 + ql;  // output col 0..191
    const int w = c >> 6;                   // 0=Q 1=K 2=V (wave-uniform per nf)
#pragma unroll
    for (int mf = 0; mf < 4; mf++) {
      const int sr = wvm * 64 + mf * 16 + g * 4;
      if (w == 0) {
#pragma unroll
        for (int r = 0; r < 4; r++)
          tq[(sr + r) * 72 + c] = (f16)(acc[mf][nf][r] * QSCL);
      } else if (w == 1) {
#pragma unroll
        for (int r = 0; r < 4; r++)
          tk[(sr + r) * 72 + (c - 64)] = (f16)acc[mf][nf][r];
      } else {
        union { f16 hh[4]; uint2 u; } z;
#pragma unroll
        for (int r = 0; r < 4; r++) z.hh[r] = (f16)acc[mf][nf][r];
        *reinterpret_cast<uint2*>(&vbuf[(c - 128) * 136 + sr]) = z.u;
      }
    }
  }
  __syncthreads();

#pragma unroll
  for (int i = 0; i < 4; i++) {  // Q,K: 128 rows x 128B each, fully coalesced
    int c = t + 256 * i;
    int s = c >> 3, pp = (c & 7) * 8;
    *reinterpret_cast<uint4*>(Q + base_sd + (size_t)(s0 + s) * DHq + pp) =
        *reinterpret_cast<const uint4*>(&tq[s * 72 + pp]);
    *reinterpret_cast<uint4*>(K + base_sd + (size_t)(s0 + s) * DHq + pp) =
        *reinterpret_cast<const uint4*>(&tk[s * 72 + pp]);
  }
#pragma unroll
  for (int i = 0; i < 4; i++) {  // V: 64 e-rows x 256B, coalesced
    int c = t + 256 * i;
    int e = c >> 4, pp = (c & 15) * 8;
    *reinterpret_cast<uint4*>(Vt + base_sd + (size_t)e * Sq + s0 + pp) =
        *reinterpret_cast<const uint4*>(&vbuf[e * 136 + pp]);
  }
}

// ---------- flash attention: 2 q-tiles/block, double-pipelined qs ----------
__global__ __launch_bounds__(256) void attn_kernel(const f16* __restrict__ Q,
                                                   const f16* __restrict__ K,
                                                   const f16* __restrict__ Vt,
                                                   float* __restrict__ out) {
  __shared__ __align__(16) f16 k_lds[2][64][72];   // [buf][kv][dh]
  __shared__ __align__(16) f16 vt_lds[2][64][72];  // [buf][dh][kv]
  __shared__ __align__(16) f16 p_lds[4][16][72];   // per-wave [q][kv]; same-wave DS FIFO

  // 768 blocks: 96 bh x 8 q-tile-pairs. XCD-local; LPT (largest KV range first).
  const int L = blockIdx.x;
  const int i = L >> 3;                        // 0..95
  const int bh = (L & 7) * Hq + (i % Hq);      // 0..95
  const int p = 7 - (i / Hq);                  // 7..0 (LPT)
  const int MT = 2 * p + 1;                    // last kv tile
  const int t = threadIdx.x;
  const int wv = t >> 6;
  const int lane = t & 63;
  const int g = lane >> 4;
  const int ql = lane & 15;

  const f16* Qb = Q + (size_t)bh * Sq * DHq;
  const f16* Kb = K + (size_t)bh * Sq * DHq;
  const f16* Vtb = Vt + (size_t)bh * DHq * Sq;
  const int b = bh / Hq, h = bh % Hq;

  const int r0 = t >> 3;          // staging row 0..31 (and +32)
  const int p0 = (t & 7) * 8;     // staging col offset (f16 elems)

  const int qg0 = 2 * p * 64 + wv * 16 + ql;
  const int qg1 = qg0 + 64;
  f16x8 qf[2][2];
  qf[0][0] = *reinterpret_cast<const f16x8*>(Qb + (size_t)qg0 * DHq + g * 8);
  qf[0][1] = *reinterpret_cast<const f16x8*>(Qb + (size_t)qg0 * DHq + 32 + g * 8);
  qf[1][0] = *reinterpret_cast<const f16x8*>(Qb + (size_t)qg1 * DHq + g * 8);
  qf[1][1] = *reinterpret_cast<const f16x8*>(Qb + (size_t)qg1 * DHq + 32 + g * 8);

  f32x4 o_acc[2][4] = {};
  float m_r[2] = { -__builtin_inff(), -__builtin_inff() };
  float l_r[2] = { 0.f, 0.f };   // per-lane partials; cross-lane reduced at epilogue

  uint4 kreg0, kreg1, vreg0, vreg1;
  kreg0 = *reinterpret_cast<const uint4*>(Kb + (size_t)r0 * DHq + p0);
  kreg1 = *reinterpret_cast<const uint4*>(Kb + (size_t)(32 + r0) * DHq + p0);
  vreg0 = *reinterpret_cast<const uint4*>(Vtb + (size_t)r0 * Sq + p0);
  vreg1 = *reinterpret_cast<const uint4*>(Vtb + (size_t)(32 + r0) * Sq + p0);
  *reinterpret_cast<uint4*>(&k_lds[0][r0][p0]) = kreg0;
  *reinterpret_cast<uint4*>(&k_lds[0][32 + r0][p0]) = kreg1;
  *reinterpret_cast<uint4*>(&vt_lds[0][r0][p0]) = vreg0;
  *reinterpret_cast<uint4*>(&vt_lds[0][32 + r0][p0]) = vreg1;
  // prefetch kt=1 (MT >= 1 always)
  kreg0 = *reinterpret_cast<const uint4*>(Kb + (size_t)(64 + r0) * DHq + p0);
  kreg1 = *reinterpret_cast<const uint4*>(Kb + (size_t)(96 + r0) * DHq + p0);
  vreg0 = *reinterpret_cast<const uint4*>(Vtb + (size_t)r0 * Sq + 64 + p0);
  vreg1 = *reinterpret_cast<const uint4*>(Vtb + (size_t)(32 + r0) * Sq + 64 + p0);
  __syncthreads();

  int cur = 0;
  for (int kt = 0; kt <= MT; kt++) {
    // top-of-iteration staging: write kt+1 into cur^1; issue loads for kt+2
    if (kt < MT) {
      *reinterpret_cast<uint4*>(&k_lds[cur ^ 1][r0][p0]) = kreg0;
      *reinterpret_cast<uint4*>(&k_lds[cur ^ 1][32 + r0][p0]) = kreg1;
      *reinterpret_cast<uint4*>(&vt_lds[cur ^ 1][r0][p0]) = vreg0;
      *reinterpret_cast<uint4*>(&vt_lds[cur ^ 1][32 + r0][p0]) = vreg1;
      if (kt + 2 <= MT) {
        const int kv0 = (kt + 2) * 64;
        kreg0 = *reinterpret_cast<const uint4*>(Kb + (size_t)(kv0 + r0) * DHq + p0);
        kreg1 = *reinterpret_cast<const uint4*>(Kb + (size_t)(kv0 + 32 + r0) * DHq + p0);
        vreg0 = *reinterpret_cast<const uint4*>(Vtb + (size_t)r0 * Sq + kv0 + p0);
        vreg1 = *reinterpret_cast<const uint4*>(Vtb + (size_t)(32 + r0) * Sq + kv0 + p0);
      }
    }

    // shared K/V fragments for both q-groups
    f16x8 kf[4][2], vf[4][2];
#pragma unroll
    for (int nt = 0; nt < 4; nt++) {
      kf[nt][0] = *reinterpret_cast<const f16x8*>(&k_lds[cur][nt * 16 + ql][g * 8]);
      kf[nt][1] = *reinterpret_cast<const f16x8*>(&k_lds[cur][nt * 16 + ql][32 + g * 8]);
      vf[nt][0] = *reinterpret_cast<const f16x8*>(&vt_lds[cur][nt * 16 + ql][g * 8]);
      vf[nt][1] = *reinterpret_cast<const f16x8*>(&vt_lds[cur][nt * 16 + ql][32 + g * 8]);
    }

    // --- QK for BOTH q-groups back-to-back (independent MFMA chains) ---
    f32x4 sf[2][4] = {};
    __builtin_amdgcn_s_setprio(1);
#pragma unroll
    for (int qs = 0; qs < 2; qs++)
#pragma unroll
      for (int nt = 0; nt < 4; nt++) {
        sf[qs][nt] = MFMA16(kf[nt][0], qf[qs][0], sf[qs][nt]);
        sf[qs][nt] = MFMA16(kf[nt][1], qf[qs][1], sf[qs][nt]);
      }
    __builtin_amdgcn_s_setprio(0);

    // --- masks ---
    if (kt == 2 * p) {  // qs=0 diagonal
#pragma unroll
      for (int nt = 0; nt < 4; nt++)
#pragma unroll
        for (int r = 0; r < 4; r++)
          if (nt * 16 + g * 4 + r > wv * 16 + ql) sf[0][nt][r] = -__builtin_inff();
    } else if (kt > 2 * p) {  // qs=0 done: full mask (exp2 -> 0, skip-rescale holds)
#pragma unroll
      for (int nt = 0; nt < 4; nt++)
#pragma unroll
        for (int r = 0; r < 4; r++) sf[0][nt][r] = -__builtin_inff();
    }
    if (kt == 2 * p + 1) {  // qs=1 diagonal
#pragma unroll
      for (int nt = 0; nt < 4; nt++)
#pragma unroll
        for (int r = 0; r < 4; r++)
          if (nt * 16 + g * 4 + r > wv * 16 + ql) sf[1][nt][r] = -__builtin_inff();
    }

    // --- max + deferred rescale for both groups ---
#pragma unroll
    for (int qs = 0; qs < 2; qs++) {
      float t0 = fmaxf(fmaxf(sf[qs][0][0], sf[qs][0][1]), fmaxf(sf[qs][0][2], sf[qs][0][3]));
      float t1 = fmaxf(fmaxf(sf[qs][1][0], sf[qs][1][1]), fmaxf(sf[qs][1][2], sf[qs][1][3]));
      float t2 = fmaxf(fmaxf(sf[qs][2][0], sf[qs][2][1]), fmaxf(sf[qs][2][2], sf[qs][2][3]));
      float t3 = fmaxf(fmaxf(sf[qs][3][0], sf[qs][3][1]), fmaxf(sf[qs][3][2], sf[qs][3][3]));
      float lm = fmaxf(fmaxf(t0, t1), fmaxf(t2, t3));
      if (!__all(lm <= m_r[qs] + 8.f)) {
        float rowmax = fmaxf(lm, __shfl_xor(lm, 16, 64));
        rowmax = fmaxf(rowmax, __shfl_xor(rowmax, 32, 64));
        float mnew = fmaxf(m_r[qs], rowmax);
        float corr = EXP2(m_r[qs] - mnew);
        l_r[qs] *= corr;
#pragma unroll
        for (int nt = 0; nt < 4; nt++) {
          o_acc[qs][nt][0] *= corr; o_acc[qs][nt][1] *= corr;
          o_acc[qs][nt][2] *= corr; o_acc[qs][nt][3] *= corr;
        }
        m_r[qs] = mnew;
      }
    }

    // --- exp + P + PV per group; qs=1's VALU overlaps qs=0's PV MFMAs ---
#pragma unroll
    for (int qs = 0; qs < 2; qs++) {
      float pv[4][4];
#pragma unroll
      for (int nt = 0; nt < 4; nt++)
#pragma unroll
        for (int r = 0; r < 4; r++) pv[nt][r] = EXP2(sf[qs][nt][r] - m_r[qs]);
      float s0 = (pv[0][0] + pv[0][1]) + (pv[0][2] + pv[0][3]);
      float s1 = (pv[1][0] + pv[1][1]) + (pv[1][2] + pv[1][3]);
      float s2 = (pv[2][0] + pv[2][1]) + (pv[2][2] + pv[2][3]);
      float s3 = (pv[3][0] + pv[3][1]) + (pv[3][2] + pv[3][3]);
      l_r[qs] += (s0 + s1) + (s2 + s3);   // per-lane partial

      // pack P pairs -> per-wave p_lds (b64 writes), read back B-fragments (b128)
#pragma unroll
      for (int nt = 0; nt < 4; nt++) {
        union { f16 hh[4]; uint2 u; } z;
        z.hh[0] = (f16)pv[nt][0]; z.hh[1] = (f16)pv[nt][1];
        z.hh[2] = (f16)pv[nt][2]; z.hh[3] = (f16)pv[nt][3];
        *reinterpret_cast<uint2*>(&p_lds[wv][ql][nt * 16 + g * 4]) = z.u;
      }
      f16x8 pf[2];
      pf[0] = *reinterpret_cast<const f16x8*>(&p_lds[wv][ql][g * 8]);
      pf[1] = *reinterpret_cast<const f16x8*>(&p_lds[wv][ql][32 + g * 8]);

      __builtin_amdgcn_s_setprio(1);
#pragma unroll
      for (int nt = 0; nt < 4; nt++) {
        o_acc[qs][nt] = MFMA16(vf[nt][0], pf[0], o_acc[qs][nt]);
        o_acc[qs][nt] = MFMA16(vf[nt][1], pf[1], o_acc[qs][nt]);
      }
      __builtin_amdgcn_s_setprio(0);
    }

    __syncthreads();
    cur ^= 1;
  }

  // epilogue: cross-lane l reduction (once), then write both q-groups
#pragma unroll
  for (int qs = 0; qs < 2; qs++) {
    const int qg = qs ? qg1 : qg0;
    float lt = l_r[qs];
    lt += __shfl_xor(lt, 16, 64);
    lt += __shfl_xor(lt, 32, 64);
    float rl = 1.0f / lt;
    float* op = out + ((size_t)(b * Sq + qg)) * (Hq * DHq) + h * DHq;
#pragma unroll
    for (int nt = 0; nt < 4; nt++) {
      float4 st = { o_acc[qs][nt][0] * rl, o_acc[qs][nt][1] * rl,
                    o_acc[qs][nt][2] * rl, o_acc[qs][nt][3] * rl };
      *reinterpret_cast<float4*>(op + nt * 16 + g * 4) = st;
    }
  }
}

extern "C" void kernel_launch(void* const* d_in, const int* in_sizes, int n_in,
                              void* d_out, int out_size, void* d_ws, size_t ws_size,
                              hipStream_t stream) {
  const float* x = (const float*)d_in[0];
  const float* Wq = (const float*)d_in[1];
  const float* Wk = (const float*)d_in[2];
  const float* Wv = (const float*)d_in[3];
  float* out = (float*)d_out;

  const size_t off_xb = 0;                    // 8192*768*2      = 12,582,912
  const size_t off_wt = 12582912;             // 2304*768*2      =  3,538,944
  const size_t off_q = 16121856;              // 96*1024*64*2    = 12,582,912
  const size_t off_k = 28704768;
  const size_t off_v = 41287680;
  const size_t need = 53870592;
  if (ws_size < need) return;

  char* ws = (char*)d_ws;
  f16* xh = (f16*)(ws + off_xb);
  f16* WT = (f16*)(ws + off_wt);
  f16* Qd = (f16*)(ws + off_q);
  f16* Kd = (f16*)(ws + off_k);
  f16* Vtd = (f16*)(ws + off_v);

  cvt_x_kernel<<<3072, 256, 0, stream>>>(x, xh);
  cvt_w_kernel<<<dim3(12, 12, 3), 256, 0, stream>>>(Wq, Wk, Wv, WT);
  proj_kernel<<<768, 256, 0, stream>>>(xh, WT, Qd, Kd, Vtd);
  attn_kernel<<<768, 256, 0, stream>>>(Qd, Kd, Vtd, out);
}

// Round 20
// 80.123 us; speedup vs baseline: 1.0587x; 1.0587x over previous
//
#include <hip/hip_runtime.h>

// MHA forward: x[8,1024,768] fp32; Wq/Wk/Wv[12,768,64] fp32 -> out[8,1024,768] fp32
// Fused cvt (x->f16 + W->f16T LDS transpose), QKV proj (f16 MFMA, 128x192 tile,
// 3-buffer depth-2 global_load_lds pipeline, counted vmcnt, XCD remap), flash attn
// (swapped-operand MFMA, dbuf + reg prefetch, 2 q-tiles/block, P via per-wave LDS,
// deferred cross-lane softmax, defer-max).  [R13 best config + fused cvt]

#define Bq 8
#define Sq 1024
#define Dq 768
#define Hq 12
#define DHq 64

typedef _Float16 f16;
typedef f16 f16x8 __attribute__((ext_vector_type(8)));
typedef float f32x4 __attribute__((ext_vector_type(4)));

#define MFMA16(a, b, c) __builtin_amdgcn_mfma_f32_16x16x32_f16(a, b, c, 0, 0, 0)

// 0.125 (1/sqrt(64)) * log2(e): folded into Q so attn works in exp2 domain
#define QSCL 0.1803368801111244f

#if __has_builtin(__builtin_amdgcn_exp2f)
#define EXP2(x) __builtin_amdgcn_exp2f(x)
#else
#define EXP2(x) exp2f(x)
#endif

__device__ __forceinline__ void gload16(const f16* g, f16* l) {
  __builtin_amdgcn_global_load_lds(
      (const __attribute__((address_space(1))) void*)g,
      (__attribute__((address_space(3))) void*)l, 16, 0, 0);
}

// ---------- fused convert: blocks 0..3071 cvt x; blocks 3072..3503 cvt W ----------
__global__ __launch_bounds__(256) void cvt_kernel(const float* __restrict__ x,
                                                  const float* __restrict__ Wq,
                                                  const float* __restrict__ Wk,
                                                  const float* __restrict__ Wv,
                                                  f16* __restrict__ xh,
                                                  f16* __restrict__ WT) {
  __shared__ float tile[64][65];
  const int blk = blockIdx.x;
  const int t = threadIdx.x;
  if (blk < 3072) {
    int i = blk * 256 + t;
    const float4* src = reinterpret_cast<const float4*>(x) + i * 2;
    float4 a = src[0], b = src[1];
    f16x8 o;
    o[0] = (f16)a.x; o[1] = (f16)a.y; o[2] = (f16)a.z; o[3] = (f16)a.w;
    o[4] = (f16)b.x; o[5] = (f16)b.y; o[6] = (f16)b.z; o[7] = (f16)b.w;
    *reinterpret_cast<f16x8*>(xh + i * 8) = o;
    return;
  }
  const int c = blk - 3072;          // 0..431
  const int kt = c % 12;
  const int h = (c / 12) % 12;
  const int w = c / 144;
  const float* W = (w == 0) ? Wq : (w == 1) ? Wk : Wv;
  const int c0 = t & 63, r4 = t >> 6;
#pragma unroll
  for (int i = 0; i < 16; i++) {
    int kr = i * 4 + r4;
    tile[kr][c0] = W[((size_t)h * Dq + kt * 64 + kr) * DHq + c0];
  }
  __syncthreads();
#pragma unroll
  for (int i = 0; i < 16; i++) {
    int e2 = i * 4 + r4;
    WT[((size_t)(w * Hq + h) * DHq + e2) * Dq + kt * 64 + c0] = (f16)tile[c0][e2];
  }
}

// ---------- QKV projection: 128x192 tile, BK=32, 3-buffer depth-2 pipeline ----------
__global__ __launch_bounds__(256) void proj_kernel(const f16* __restrict__ xh,
                                                   const f16* __restrict__ WT,
                                                   f16* __restrict__ Q,
                                                   f16* __restrict__ K,
                                                   f16* __restrict__ Vt) {
  __shared__ __align__(1024) f16 smem[30720];  // A 3x4096 @0, B 3x6144 @12288

  const int L = blockIdx.x;            // 0..767
  const int j = L >> 3;                // 0..95
  const int mt = (L & 7) + 8 * (j & 7);  // 0..63, mt%8 == L%8 (XCD-local x tiles)
  const int h = j >> 3;                // 0..11
  const int row0 = mt * 128;
  const int t = threadIdx.x;
  const int wv = t >> 6;
  const int lane = t & 63;
  const int g = lane >> 4;
  const int ql = lane & 15;
  const int wvm = wv >> 1, wvn = wv & 1;

  const int lr = lane >> 2;                          // row within 16-row chunk
  const int scg = (lane & 3) ^ ((lane >> 3) & 3);    // pre-swizzled source unit

  const f16* xsrc = xh + (size_t)row0 * Dq;
  const f16* wsrc = WT + (size_t)h * DHq * Dq;

  const f16* gA0 = xsrc + (size_t)(wv * 32 + lr) * Dq + scg * 8;
  const f16* gA1 = gA0 + (size_t)16 * Dq;
  const int n0 = wv * 48 + lr, n1 = n0 + 16, n2 = n0 + 32;
  const f16* gB0 = wsrc + ((size_t)(n0 >> 6) * Hq * DHq + (n0 & 63)) * Dq + scg * 8;
  const f16* gB1 = wsrc + ((size_t)(n1 >> 6) * Hq * DHq + (n1 & 63)) * Dq + scg * 8;
  const f16* gB2 = wsrc + ((size_t)(n2 >> 6) * Hq * DHq + (n2 & 63)) * Dq + scg * 8;

  f32x4 acc[4][6] = {};

#define PROJ_STAGE(buf)                                              \
  do {                                                               \
    f16* sA_ = smem + (buf) * 4096 + wv * 1024;                      \
    f16* sB_ = smem + 12288 + (buf) * 6144 + wv * 1536;              \
    gload16(gA0, sA_); gload16(gA1, sA_ + 512);                      \
    gload16(gB0, sB_); gload16(gB1, sB_ + 512);                      \
    gload16(gB2, sB_ + 1024);                                        \
    gA0 += 32; gA1 += 32; gB0 += 32; gB1 += 32; gB2 += 32;           \
  } while (0)

  PROJ_STAGE(0);
  PROJ_STAGE(1);

  const int rq = (g ^ ((ql >> 1) & 3)) * 8;  // swizzled read unit offset (elems)
  const f16* rA = smem + (wvm * 64 + ql) * 32 + rq;
  const f16* rB = smem + 12288 + (wvn * 96 + ql) * 32 + rq;

#pragma unroll
  for (int step = 0; step < 24; step++) {
    if (step < 23) asm volatile("s_waitcnt vmcnt(5) lgkmcnt(0)" ::: "memory");
    else           asm volatile("s_waitcnt vmcnt(0) lgkmcnt(0)" ::: "memory");
    __builtin_amdgcn_s_barrier();
    __builtin_amdgcn_sched_barrier(0);
    if (step < 22) PROJ_STAGE((step + 2) % 3);
    const int cur = step % 3;
    f16x8 af[4], bf[6];
#pragma unroll
    for (int mf = 0; mf < 4; mf++)
      af[mf] = *reinterpret_cast<const f16x8*>(rA + cur * 4096 + mf * 512);
#pragma unroll
    for (int nf = 0; nf < 6; nf++)
      bf[nf] = *reinterpret_cast<const f16x8*>(rB + cur * 6144 + nf * 512);
    __builtin_amdgcn_s_setprio(1);
#pragma unroll
    for (int mf = 0; mf < 4; mf++)
#pragma unroll
      for (int nf = 0; nf < 6; nf++)
        acc[mf][nf] = MFMA16(af[mf], bf[nf], acc[mf][nf]);
    __builtin_amdgcn_s_setprio(0);
  }
#undef PROJ_STAGE
  __syncthreads();  // all LDS reads done before smem reuse below

  const int b = row0 >> 10;
  const int s0 = row0 & 1023;
  const size_t base_sd = ((size_t)(b * Hq + h) * Sq) * DHq;

#pragma unroll
  for (int nf = 0; nf < 6; nf++) {
    const int c = wvn * 96 + nf * 16 + ql;
    const int w = c >> 6;
    if (w < 2) {
      f16* dst = (w == 0 ? Q : K);
      const float scl = (w == 0) ? QSCL : 1.0f;
      const int e = c & 63;
#pragma unroll
      for (int mf = 0; mf < 4; mf++) {
        const int sr = wvm * 64 + mf * 16 + g * 4;
#pragma unroll
        for (int r = 0; r < 4; r++)
          dst[base_sd + (size_t)(s0 + sr + r) * DHq + e] = (f16)(acc[mf][nf][r] * scl);
      }
    }
  }

  f16* vbuf = smem;
#pragma unroll
  for (int nf = 2; nf < 6; nf++) {
    if (wvn == 1) {
      const int e = (96 + nf * 16 + ql) & 63;
#pragma unroll
      for (int mf = 0; mf < 4; mf++) {
        const int sr = wvm * 64 + mf * 16 + g * 4;
        union { f16 hh[4]; uint2 u; } z;
#pragma unroll
        for (int r = 0; r < 4; r++) z.hh[r] = (f16)acc[mf][nf][r];
        *reinterpret_cast<uint2*>(&vbuf[e * 136 + sr]) = z.u;
      }
    }
  }
  __syncthreads();
#pragma unroll
  for (int i = 0; i < 4; i++) {
    int c = t + 256 * i;
    int e = c >> 4, p = (c & 15) * 8;
    *reinterpret_cast<uint4*>(Vt + base_sd + (size_t)e * Sq + s0 + p) =
        *reinterpret_cast<const uint4*>(vbuf + e * 136 + p);
  }
}

// ---------- flash attention: 2 q-tiles/block, deferred cross-lane softmax ----------
__global__ __launch_bounds__(256) void attn_kernel(const f16* __restrict__ Q,
                                                   const f16* __restrict__ K,
                                                   const f16* __restrict__ Vt,
                                                   float* __restrict__ out) {
  __shared__ __align__(16) f16 k_lds[2][64][72];   // [buf][kv][dh]
  __shared__ __align__(16) f16 vt_lds[2][64][72];  // [buf][dh][kv]
  __shared__ __align__(16) f16 p_lds[4][16][72];   // per-wave [q][kv], no barrier needed

  // 768 blocks: 96 bh x 8 q-tile-pairs. XCD-local; LPT (largest KV range first).
  const int L = blockIdx.x;
  const int i = L >> 3;                        // 0..95
  const int bh = (L & 7) * Hq + (i % Hq);      // 0..95
  const int p = 7 - (i / Hq);                  // 7..0 (LPT)
  const int MT = 2 * p + 1;                    // last kv tile
  const int t = threadIdx.x;
  const int wv = t >> 6;
  const int lane = t & 63;
  const int g = lane >> 4;
  const int ql = lane & 15;

  const f16* Qb = Q + (size_t)bh * Sq * DHq;
  const f16* Kb = K + (size_t)bh * Sq * DHq;
  const f16* Vtb = Vt + (size_t)bh * DHq * Sq;
  const int b = bh / Hq, h = bh % Hq;

  const int r0 = t >> 3;          // staging row 0..31 (and +32)
  const int p0 = (t & 7) * 8;     // staging col offset (f16 elems)

  const int qg0 = 2 * p * 64 + wv * 16 + ql;
  const int qg1 = qg0 + 64;
  f16x8 qf[2][2];
  qf[0][0] = *reinterpret_cast<const f16x8*>(Qb + (size_t)qg0 * DHq + g * 8);
  qf[0][1] = *reinterpret_cast<const f16x8*>(Qb + (size_t)qg0 * DHq + 32 + g * 8);
  qf[1][0] = *reinterpret_cast<const f16x8*>(Qb + (size_t)qg1 * DHq + g * 8);
  qf[1][1] = *reinterpret_cast<const f16x8*>(Qb + (size_t)qg1 * DHq + 32 + g * 8);

  f32x4 o_acc[2][4] = {};
  float m_r[2] = { -__builtin_inff(), -__builtin_inff() };
  float l_r[2] = { 0.f, 0.f };   // per-lane partials; cross-lane reduced at epilogue

  uint4 kreg0, kreg1, vreg0, vreg1;
  kreg0 = *reinterpret_cast<const uint4*>(Kb + (size_t)r0 * DHq + p0);
  kreg1 = *reinterpret_cast<const uint4*>(Kb + (size_t)(32 + r0) * DHq + p0);
  vreg0 = *reinterpret_cast<const uint4*>(Vtb + (size_t)r0 * Sq + p0);
  vreg1 = *reinterpret_cast<const uint4*>(Vtb + (size_t)(32 + r0) * Sq + p0);
  *reinterpret_cast<uint4*>(&k_lds[0][r0][p0]) = kreg0;
  *reinterpret_cast<uint4*>(&k_lds[0][32 + r0][p0]) = kreg1;
  *reinterpret_cast<uint4*>(&vt_lds[0][r0][p0]) = vreg0;
  *reinterpret_cast<uint4*>(&vt_lds[0][32 + r0][p0]) = vreg1;
  // prefetch kt=1 (MT >= 1 always)
  kreg0 = *reinterpret_cast<const uint4*>(Kb + (size_t)(64 + r0) * DHq + p0);
  kreg1 = *reinterpret_cast<const uint4*>(Kb + (size_t)(96 + r0) * DHq + p0);
  vreg0 = *reinterpret_cast<const uint4*>(Vtb + (size_t)r0 * Sq + 64 + p0);
  vreg1 = *reinterpret_cast<const uint4*>(Vtb + (size_t)(32 + r0) * Sq + 64 + p0);
  __syncthreads();

  int cur = 0;
  for (int kt = 0; kt <= MT; kt++) {
    // top-of-iteration staging: write kt+1 into cur^1; issue loads for kt+2
    if (kt < MT) {
      *reinterpret_cast<uint4*>(&k_lds[cur ^ 1][r0][p0]) = kreg0;
      *reinterpret_cast<uint4*>(&k_lds[cur ^ 1][32 + r0][p0]) = kreg1;
      *reinterpret_cast<uint4*>(&vt_lds[cur ^ 1][r0][p0]) = vreg0;
      *reinterpret_cast<uint4*>(&vt_lds[cur ^ 1][32 + r0][p0]) = vreg1;
      if (kt + 2 <= MT) {
        const int kv0 = (kt + 2) * 64;
        kreg0 = *reinterpret_cast<const uint4*>(Kb + (size_t)(kv0 + r0) * DHq + p0);
        kreg1 = *reinterpret_cast<const uint4*>(Kb + (size_t)(kv0 + 32 + r0) * DHq + p0);
        vreg0 = *reinterpret_cast<const uint4*>(Vtb + (size_t)r0 * Sq + kv0 + p0);
        vreg1 = *reinterpret_cast<const uint4*>(Vtb + (size_t)(32 + r0) * Sq + kv0 + p0);
      }
    }

    // shared K/V fragments for both q-groups
    f16x8 kf[4][2], vf[4][2];
#pragma unroll
    for (int nt = 0; nt < 4; nt++) {
      kf[nt][0] = *reinterpret_cast<const f16x8*>(&k_lds[cur][nt * 16 + ql][g * 8]);
      kf[nt][1] = *reinterpret_cast<const f16x8*>(&k_lds[cur][nt * 16 + ql][32 + g * 8]);
      vf[nt][0] = *reinterpret_cast<const f16x8*>(&vt_lds[cur][nt * 16 + ql][g * 8]);
      vf[nt][1] = *reinterpret_cast<const f16x8*>(&vt_lds[cur][nt * 16 + ql][32 + g * 8]);
    }

#pragma unroll
    for (int qs = 0; qs < 2; qs++) {
      if (qs == 0 && kt > 2 * p) continue;  // lower tile done (wave-uniform)
      // S^T = K Q^T
      f32x4 sf[4] = {};
      __builtin_amdgcn_s_setprio(1);
#pragma unroll
      for (int nt = 0; nt < 4; nt++) {
        sf[nt] = MFMA16(kf[nt][0], qf[qs][0], sf[nt]);
        sf[nt] = MFMA16(kf[nt][1], qf[qs][1], sf[nt]);
      }
      __builtin_amdgcn_s_setprio(0);

      if (kt == 2 * p + qs) {  // diagonal tile of this q-group
#pragma unroll
        for (int nt = 0; nt < 4; nt++)
#pragma unroll
          for (int r = 0; r < 4; r++)
            if (nt * 16 + g * 4 + r > wv * 16 + ql) sf[nt][r] = -__builtin_inff();
      }

      // per-lane max of this tile (no cross-lane in common path)
      float t0 = fmaxf(fmaxf(sf[0][0], sf[0][1]), fmaxf(sf[0][2], sf[0][3]));
      float t1 = fmaxf(fmaxf(sf[1][0], sf[1][1]), fmaxf(sf[1][2], sf[1][3]));
      float t2 = fmaxf(fmaxf(sf[2][0], sf[2][1]), fmaxf(sf[2][2], sf[2][3]));
      float t3 = fmaxf(fmaxf(sf[3][0], sf[3][1]), fmaxf(sf[3][2], sf[3][3]));
      float lm = fmaxf(fmaxf(t0, t1), fmaxf(t2, t3));

      // defer-max (T13): cross-lane reduce + rescale only when some lane exceeds m+8
      if (!__all(lm <= m_r[qs] + 8.f)) {
        float rowmax = fmaxf(lm, __shfl_xor(lm, 16, 64));
        rowmax = fmaxf(rowmax, __shfl_xor(rowmax, 32, 64));
        float mnew = fmaxf(m_r[qs], rowmax);
        float corr = EXP2(m_r[qs] - mnew);
        l_r[qs] *= corr;
#pragma unroll
        for (int nt = 0; nt < 4; nt++) {
          o_acc[qs][nt][0] *= corr; o_acc[qs][nt][1] *= corr;
          o_acc[qs][nt][2] *= corr; o_acc[qs][nt][3] *= corr;
        }
        m_r[qs] = mnew;
      }

      float pv[4][4];
#pragma unroll
      for (int nt = 0; nt < 4; nt++)
#pragma unroll
        for (int r = 0; r < 4; r++) pv[nt][r] = EXP2(sf[nt][r] - m_r[qs]);
      float s0 = (pv[0][0] + pv[0][1]) + (pv[0][2] + pv[0][3]);
      float s1 = (pv[1][0] + pv[1][1]) + (pv[1][2] + pv[1][3]);
      float s2 = (pv[2][0] + pv[2][1]) + (pv[2][2] + pv[2][3]);
      float s3 = (pv[3][0] + pv[3][1]) + (pv[3][2] + pv[3][3]);
      l_r[qs] += (s0 + s1) + (s2 + s3);   // per-lane partial

      // pack P pairs -> per-wave p_lds (b64 writes), read back B-fragments (b128)
#pragma unroll
      for (int nt = 0; nt < 4; nt++) {
        union { f16 hh[4]; uint2 u; } z;
        z.hh[0] = (f16)pv[nt][0]; z.hh[1] = (f16)pv[nt][1];
        z.hh[2] = (f16)pv[nt][2]; z.hh[3] = (f16)pv[nt][3];
        *reinterpret_cast<uint2*>(&p_lds[wv][ql][nt * 16 + g * 4]) = z.u;
      }
      f16x8 pf[2];
      pf[0] = *reinterpret_cast<const f16x8*>(&p_lds[wv][ql][g * 8]);
      pf[1] = *reinterpret_cast<const f16x8*>(&p_lds[wv][ql][32 + g * 8]);

      // O^T += V^T P^T
      __builtin_amdgcn_s_setprio(1);
#pragma unroll
      for (int nt = 0; nt < 4; nt++) {
        o_acc[qs][nt] = MFMA16(vf[nt][0], pf[0], o_acc[qs][nt]);
        o_acc[qs][nt] = MFMA16(vf[nt][1], pf[1], o_acc[qs][nt]);
      }
      __builtin_amdgcn_s_setprio(0);
    }

    __syncthreads();
    cur ^= 1;
  }

  // epilogue: cross-lane l reduction (once), then write both q-groups
#pragma unroll
  for (int qs = 0; qs < 2; qs++) {
    const int qg = qs ? qg1 : qg0;
    float lt = l_r[qs];
    lt += __shfl_xor(lt, 16, 64);
    lt += __shfl_xor(lt, 32, 64);
    float rl = 1.0f / lt;
    float* op = out + ((size_t)(b * Sq + qg)) * (Hq * DHq) + h * DHq;
#pragma unroll
    for (int nt = 0; nt < 4; nt++) {
      float4 st = { o_acc[qs][nt][0] * rl, o_acc[qs][nt][1] * rl,
                    o_acc[qs][nt][2] * rl, o_acc[qs][nt][3] * rl };
      *reinterpret_cast<float4*>(op + nt * 16 + g * 4) = st;
    }
  }
}

extern "C" void kernel_launch(void* const* d_in, const int* in_sizes, int n_in,
                              void* d_out, int out_size, void* d_ws, size_t ws_size,
                              hipStream_t stream) {
  const float* x = (const float*)d_in[0];
  const float* Wq = (const float*)d_in[1];
  const float* Wk = (const float*)d_in[2];
  const float* Wv = (const float*)d_in[3];
  float* out = (float*)d_out;

  const size_t off_xb = 0;                    // 8192*768*2      = 12,582,912
  const size_t off_wt = 12582912;             // 2304*768*2      =  3,538,944
  const size_t off_q = 16121856;              // 96*1024*64*2    = 12,582,912
  const size_t off_k = 28704768;
  const size_t off_v = 41287680;
  const size_t need = 53870592;
  if (ws_size < need) return;

  char* ws = (char*)d_ws;
  f16* xh = (f16*)(ws + off_xb);
  f16* WT = (f16*)(ws + off_wt);
  f16* Qd = (f16*)(ws + off_q);
  f16* Kd = (f16*)(ws + off_k);
  f16* Vtd = (f16*)(ws + off_v);

  cvt_kernel<<<3504, 256, 0, stream>>>(x, Wq, Wk, Wv, xh, WT);
  proj_kernel<<<768, 256, 0, stream>>>(xh, WT, Qd, Kd, Vtd);
  attn_kernel<<<768, 256, 0, stream>>>(Qd, Kd, Vtd, out);
}

// Round 21
// 79.974 us; speedup vs baseline: 1.0607x; 1.0019x over previous
//
#include <hip/hip_runtime.h>

// MHA forward: x[8,1024,768] fp32; Wq/Wk/Wv[12,768,64] fp32 -> out[8,1024,768] fp32
// Fused cvt (x->f16 + W->f16T LDS transpose), QKV proj (f16 MFMA, 128x192 tile,
// 3-buffer depth-2 global_load_lds pipeline, counted vmcnt, XCD remap), flash attn
// (swapped-operand MFMA, dbuf + reg prefetch, 2 q-tiles/block, P via per-wave LDS
// with stride-88 rows (4-way read banks vs 8-way at 72), deferred softmax, defer-max).

#define Bq 8
#define Sq 1024
#define Dq 768
#define Hq 12
#define DHq 64

typedef _Float16 f16;
typedef f16 f16x8 __attribute__((ext_vector_type(8)));
typedef float f32x4 __attribute__((ext_vector_type(4)));

#define MFMA16(a, b, c) __builtin_amdgcn_mfma_f32_16x16x32_f16(a, b, c, 0, 0, 0)

// 0.125 (1/sqrt(64)) * log2(e): folded into Q so attn works in exp2 domain
#define QSCL 0.1803368801111244f

#if __has_builtin(__builtin_amdgcn_exp2f)
#define EXP2(x) __builtin_amdgcn_exp2f(x)
#else
#define EXP2(x) exp2f(x)
#endif

__device__ __forceinline__ void gload16(const f16* g, f16* l) {
  __builtin_amdgcn_global_load_lds(
      (const __attribute__((address_space(1))) void*)g,
      (__attribute__((address_space(3))) void*)l, 16, 0, 0);
}

// ---------- fused convert: blocks 0..3071 cvt x; blocks 3072..3503 cvt W ----------
__global__ __launch_bounds__(256) void cvt_kernel(const float* __restrict__ x,
                                                  const float* __restrict__ Wq,
                                                  const float* __restrict__ Wk,
                                                  const float* __restrict__ Wv,
                                                  f16* __restrict__ xh,
                                                  f16* __restrict__ WT) {
  __shared__ float tile[64][65];
  const int blk = blockIdx.x;
  const int t = threadIdx.x;
  if (blk < 3072) {
    int i = blk * 256 + t;
    const float4* src = reinterpret_cast<const float4*>(x) + i * 2;
    float4 a = src[0], b = src[1];
    f16x8 o;
    o[0] = (f16)a.x; o[1] = (f16)a.y; o[2] = (f16)a.z; o[3] = (f16)a.w;
    o[4] = (f16)b.x; o[5] = (f16)b.y; o[6] = (f16)b.z; o[7] = (f16)b.w;
    *reinterpret_cast<f16x8*>(xh + i * 8) = o;
    return;
  }
  const int c = blk - 3072;          // 0..431
  const int kt = c % 12;
  const int h = (c / 12) % 12;
  const int w = c / 144;
  const float* W = (w == 0) ? Wq : (w == 1) ? Wk : Wv;
  const int c0 = t & 63, r4 = t >> 6;
#pragma unroll
  for (int i = 0; i < 16; i++) {
    int kr = i * 4 + r4;
    tile[kr][c0] = W[((size_t)h * Dq + kt * 64 + kr) * DHq + c0];
  }
  __syncthreads();
#pragma unroll
  for (int i = 0; i < 16; i++) {
    int e2 = i * 4 + r4;
    WT[((size_t)(w * Hq + h) * DHq + e2) * Dq + kt * 64 + c0] = (f16)tile[c0][e2];
  }
}

// ---------- QKV projection: 128x192 tile, BK=32, 3-buffer depth-2 pipeline ----------
__global__ __launch_bounds__(256) void proj_kernel(const f16* __restrict__ xh,
                                                   const f16* __restrict__ WT,
                                                   f16* __restrict__ Q,
                                                   f16* __restrict__ K,
                                                   f16* __restrict__ Vt) {
  __shared__ __align__(1024) f16 smem[30720];  // A 3x4096 @0, B 3x6144 @12288

  const int L = blockIdx.x;            // 0..767
  const int j = L >> 3;                // 0..95
  const int mt = (L & 7) + 8 * (j & 7);  // 0..63, mt%8 == L%8 (XCD-local x tiles)
  const int h = j >> 3;                // 0..11
  const int row0 = mt * 128;
  const int t = threadIdx.x;
  const int wv = t >> 6;
  const int lane = t & 63;
  const int g = lane >> 4;
  const int ql = lane & 15;
  const int wvm = wv >> 1, wvn = wv & 1;

  const int lr = lane >> 2;                          // row within 16-row chunk
  const int scg = (lane & 3) ^ ((lane >> 3) & 3);    // pre-swizzled source unit

  const f16* xsrc = xh + (size_t)row0 * Dq;
  const f16* wsrc = WT + (size_t)h * DHq * Dq;

  const f16* gA0 = xsrc + (size_t)(wv * 32 + lr) * Dq + scg * 8;
  const f16* gA1 = gA0 + (size_t)16 * Dq;
  const int n0 = wv * 48 + lr, n1 = n0 + 16, n2 = n0 + 32;
  const f16* gB0 = wsrc + ((size_t)(n0 >> 6) * Hq * DHq + (n0 & 63)) * Dq + scg * 8;
  const f16* gB1 = wsrc + ((size_t)(n1 >> 6) * Hq * DHq + (n1 & 63)) * Dq + scg * 8;
  const f16* gB2 = wsrc + ((size_t)(n2 >> 6) * Hq * DHq + (n2 & 63)) * Dq + scg * 8;

  f32x4 acc[4][6] = {};

#define PROJ_STAGE(buf)                                              \
  do {                                                               \
    f16* sA_ = smem + (buf) * 4096 + wv * 1024;                      \
    f16* sB_ = smem + 12288 + (buf) * 6144 + wv * 1536;              \
    gload16(gA0, sA_); gload16(gA1, sA_ + 512);                      \
    gload16(gB0, sB_); gload16(gB1, sB_ + 512);                      \
    gload16(gB2, sB_ + 1024);                                        \
    gA0 += 32; gA1 += 32; gB0 += 32; gB1 += 32; gB2 += 32;           \
  } while (0)

  PROJ_STAGE(0);
  PROJ_STAGE(1);

  const int rq = (g ^ ((ql >> 1) & 3)) * 8;  // swizzled read unit offset (elems)
  const f16* rA = smem + (wvm * 64 + ql) * 32 + rq;
  const f16* rB = smem + 12288 + (wvn * 96 + ql) * 32 + rq;

#pragma unroll
  for (int step = 0; step < 24; step++) {
    if (step < 23) asm volatile("s_waitcnt vmcnt(5) lgkmcnt(0)" ::: "memory");
    else           asm volatile("s_waitcnt vmcnt(0) lgkmcnt(0)" ::: "memory");
    __builtin_amdgcn_s_barrier();
    __builtin_amdgcn_sched_barrier(0);
    if (step < 22) PROJ_STAGE((step + 2) % 3);
    const int cur = step % 3;
    f16x8 af[4], bf[6];
#pragma unroll
    for (int mf = 0; mf < 4; mf++)
      af[mf] = *reinterpret_cast<const f16x8*>(rA + cur * 4096 + mf * 512);
#pragma unroll
    for (int nf = 0; nf < 6; nf++)
      bf[nf] = *reinterpret_cast<const f16x8*>(rB + cur * 6144 + nf * 512);
    __builtin_amdgcn_s_setprio(1);
#pragma unroll
    for (int mf = 0; mf < 4; mf++)
#pragma unroll
      for (int nf = 0; nf < 6; nf++)
        acc[mf][nf] = MFMA16(af[mf], bf[nf], acc[mf][nf]);
    __builtin_amdgcn_s_setprio(0);
  }
#undef PROJ_STAGE
  __syncthreads();  // all LDS reads done before smem reuse below

  const int b = row0 >> 10;
  const int s0 = row0 & 1023;
  const size_t base_sd = ((size_t)(b * Hq + h) * Sq) * DHq;

#pragma unroll
  for (int nf = 0; nf < 6; nf++) {
    const int c = wvn * 96 + nf * 16 + ql;
    const int w = c >> 6;
    if (w < 2) {
      f16* dst = (w == 0 ? Q : K);
      const float scl = (w == 0) ? QSCL : 1.0f;
      const int e = c & 63;
#pragma unroll
      for (int mf = 0; mf < 4; mf++) {
        const int sr = wvm * 64 + mf * 16 + g * 4;
#pragma unroll
        for (int r = 0; r < 4; r++)
          dst[base_sd + (size_t)(s0 + sr + r) * DHq + e] = (f16)(acc[mf][nf][r] * scl);
      }
    }
  }

  f16* vbuf = smem;
#pragma unroll
  for (int nf = 2; nf < 6; nf++) {
    if (wvn == 1) {
      const int e = (96 + nf * 16 + ql) & 63;
#pragma unroll
      for (int mf = 0; mf < 4; mf++) {
        const int sr = wvm * 64 + mf * 16 + g * 4;
        union { f16 hh[4]; uint2 u; } z;
#pragma unroll
        for (int r = 0; r < 4; r++) z.hh[r] = (f16)acc[mf][nf][r];
        *reinterpret_cast<uint2*>(&vbuf[e * 136 + sr]) = z.u;
      }
    }
  }
  __syncthreads();
#pragma unroll
  for (int i = 0; i < 4; i++) {
    int c = t + 256 * i;
    int e = c >> 4, p = (c & 15) * 8;
    *reinterpret_cast<uint4*>(Vt + base_sd + (size_t)e * Sq + s0 + p) =
        *reinterpret_cast<const uint4*>(vbuf + e * 136 + p);
  }
}

// ---------- flash attention: 2 q-tiles/block, deferred cross-lane softmax ----------
__global__ __launch_bounds__(256) void attn_kernel(const f16* __restrict__ Q,
                                                   const f16* __restrict__ K,
                                                   const f16* __restrict__ Vt,
                                                   float* __restrict__ out) {
  __shared__ __align__(16) f16 k_lds[2][64][72];   // [buf][kv][dh]
  __shared__ __align__(16) f16 vt_lds[2][64][72];  // [buf][dh][kv]
  __shared__ __align__(16) f16 p_lds[4][16][88];   // per-wave [q][kv]; stride 88 -> 4-way read banks

  // 768 blocks: 96 bh x 8 q-tile-pairs. XCD-local; LPT (largest KV range first).
  const int L = blockIdx.x;
  const int i = L >> 3;                        // 0..95
  const int bh = (L & 7) * Hq + (i % Hq);      // 0..95
  const int p = 7 - (i / Hq);                  // 7..0 (LPT)
  const int MT = 2 * p + 1;                    // last kv tile
  const int t = threadIdx.x;
  const int wv = t >> 6;
  const int lane = t & 63;
  const int g = lane >> 4;
  const int ql = lane & 15;

  const f16* Qb = Q + (size_t)bh * Sq * DHq;
  const f16* Kb = K + (size_t)bh * Sq * DHq;
  const f16* Vtb = Vt + (size_t)bh * DHq * Sq;
  const int b = bh / Hq, h = bh % Hq;

  const int r0 = t >> 3;          // staging row 0..31 (and +32)
  const int p0 = (t & 7) * 8;     // staging col offset (f16 elems)

  const int qg0 = 2 * p * 64 + wv * 16 + ql;
  const int qg1 = qg0 + 64;
  f16x8 qf[2][2];
  qf[0][0] = *reinterpret_cast<const f16x8*>(Qb + (size_t)qg0 * DHq + g * 8);
  qf[0][1] = *reinterpret_cast<const f16x8*>(Qb + (size_t)qg0 * DHq + 32 + g * 8);
  qf[1][0] = *reinterpret_cast<const f16x8*>(Qb + (size_t)qg1 * DHq + g * 8);
  qf[1][1] = *reinterpret_cast<const f16x8*>(Qb + (size_t)qg1 * DHq + 32 + g * 8);

  f32x4 o_acc[2][4] = {};
  float m_r[2] = { -__builtin_inff(), -__builtin_inff() };
  float l_r[2] = { 0.f, 0.f };   // per-lane partials; cross-lane reduced at epilogue

  uint4 kreg0, kreg1, vreg0, vreg1;
  kreg0 = *reinterpret_cast<const uint4*>(Kb + (size_t)r0 * DHq + p0);
  kreg1 = *reinterpret_cast<const uint4*>(Kb + (size_t)(32 + r0) * DHq + p0);
  vreg0 = *reinterpret_cast<const uint4*>(Vtb + (size_t)r0 * Sq + p0);
  vreg1 = *reinterpret_cast<const uint4*>(Vtb + (size_t)(32 + r0) * Sq + p0);
  *reinterpret_cast<uint4*>(&k_lds[0][r0][p0]) = kreg0;
  *reinterpret_cast<uint4*>(&k_lds[0][32 + r0][p0]) = kreg1;
  *reinterpret_cast<uint4*>(&vt_lds[0][r0][p0]) = vreg0;
  *reinterpret_cast<uint4*>(&vt_lds[0][32 + r0][p0]) = vreg1;
  // prefetch kt=1 (MT >= 1 always)
  kreg0 = *reinterpret_cast<const uint4*>(Kb + (size_t)(64 + r0) * DHq + p0);
  kreg1 = *reinterpret_cast<const uint4*>(Kb + (size_t)(96 + r0) * DHq + p0);
  vreg0 = *reinterpret_cast<const uint4*>(Vtb + (size_t)r0 * Sq + 64 + p0);
  vreg1 = *reinterpret_cast<const uint4*>(Vtb + (size_t)(32 + r0) * Sq + 64 + p0);
  __syncthreads();

  int cur = 0;
  for (int kt = 0; kt <= MT; kt++) {
    // top-of-iteration staging: write kt+1 into cur^1; issue loads for kt+2
    if (kt < MT) {
      *reinterpret_cast<uint4*>(&k_lds[cur ^ 1][r0][p0]) = kreg0;
      *reinterpret_cast<uint4*>(&k_lds[cur ^ 1][32 + r0][p0]) = kreg1;
      *reinterpret_cast<uint4*>(&vt_lds[cur ^ 1][r0][p0]) = vreg0;
      *reinterpret_cast<uint4*>(&vt_lds[cur ^ 1][32 + r0][p0]) = vreg1;
      if (kt + 2 <= MT) {
        const int kv0 = (kt + 2) * 64;
        kreg0 = *reinterpret_cast<const uint4*>(Kb + (size_t)(kv0 + r0) * DHq + p0);
        kreg1 = *reinterpret_cast<const uint4*>(Kb + (size_t)(kv0 + 32 + r0) * DHq + p0);
        vreg0 = *reinterpret_cast<const uint4*>(Vtb + (size_t)r0 * Sq + kv0 + p0);
        vreg1 = *reinterpret_cast<const uint4*>(Vtb + (size_t)(32 + r0) * Sq + kv0 + p0);
      }
    }

    // shared K/V fragments for both q-groups
    f16x8 kf[4][2], vf[4][2];
#pragma unroll
    for (int nt = 0; nt < 4; nt++) {
      kf[nt][0] = *reinterpret_cast<const f16x8*>(&k_lds[cur][nt * 16 + ql][g * 8]);
      kf[nt][1] = *reinterpret_cast<const f16x8*>(&k_lds[cur][nt * 16 + ql][32 + g * 8]);
      vf[nt][0] = *reinterpret_cast<const f16x8*>(&vt_lds[cur][nt * 16 + ql][g * 8]);
      vf[nt][1] = *reinterpret_cast<const f16x8*>(&vt_lds[cur][nt * 16 + ql][32 + g * 8]);
    }

#pragma unroll
    for (int qs = 0; qs < 2; qs++) {
      if (qs == 0 && kt > 2 * p) continue;  // lower tile done (wave-uniform)
      // S^T = K Q^T
      f32x4 sf[4] = {};
      __builtin_amdgcn_s_setprio(1);
#pragma unroll
      for (int nt = 0; nt < 4; nt++) {
        sf[nt] = MFMA16(kf[nt][0], qf[qs][0], sf[nt]);
        sf[nt] = MFMA16(kf[nt][1], qf[qs][1], sf[nt]);
      }
      __builtin_amdgcn_s_setprio(0);

      if (kt == 2 * p + qs) {  // diagonal tile of this q-group
#pragma unroll
        for (int nt = 0; nt < 4; nt++)
#pragma unroll
          for (int r = 0; r < 4; r++)
            if (nt * 16 + g * 4 + r > wv * 16 + ql) sf[nt][r] = -__builtin_inff();
      }

      // per-lane max of this tile (no cross-lane in common path)
      float t0 = fmaxf(fmaxf(sf[0][0], sf[0][1]), fmaxf(sf[0][2], sf[0][3]));
      float t1 = fmaxf(fmaxf(sf[1][0], sf[1][1]), fmaxf(sf[1][2], sf[1][3]));
      float t2 = fmaxf(fmaxf(sf[2][0], sf[2][1]), fmaxf(sf[2][2], sf[2][3]));
      float t3 = fmaxf(fmaxf(sf[3][0], sf[3][1]), fmaxf(sf[3][2], sf[3][3]));
      float lm = fmaxf(fmaxf(t0, t1), fmaxf(t2, t3));

      // defer-max (T13): cross-lane reduce + rescale only when some lane exceeds m+8
      if (!__all(lm <= m_r[qs] + 8.f)) {
        float rowmax = fmaxf(lm, __shfl_xor(lm, 16, 64));
        rowmax = fmaxf(rowmax, __shfl_xor(rowmax, 32, 64));
        float mnew = fmaxf(m_r[qs], rowmax);
        float corr = EXP2(m_r[qs] - mnew);
        l_r[qs] *= corr;
#pragma unroll
        for (int nt = 0; nt < 4; nt++) {
          o_acc[qs][nt][0] *= corr; o_acc[qs][nt][1] *= corr;
          o_acc[qs][nt][2] *= corr; o_acc[qs][nt][3] *= corr;
        }
        m_r[qs] = mnew;
      }

      float pv[4][4];
#pragma unroll
      for (int nt = 0; nt < 4; nt++)
#pragma unroll
        for (int r = 0; r < 4; r++) pv[nt][r] = EXP2(sf[nt][r] - m_r[qs]);
      float s0 = (pv[0][0] + pv[0][1]) + (pv[0][2] + pv[0][3]);
      float s1 = (pv[1][0] + pv[1][1]) + (pv[1][2] + pv[1][3]);
      float s2 = (pv[2][0] + pv[2][1]) + (pv[2][2] + pv[2][3]);
      float s3 = (pv[3][0] + pv[3][1]) + (pv[3][2] + pv[3][3]);
      l_r[qs] += (s0 + s1) + (s2 + s3);   // per-lane partial

      // pack P pairs -> per-wave p_lds (b64 writes), read back B-fragments (b128)
#pragma unroll
      for (int nt = 0; nt < 4; nt++) {
        union { f16 hh[4]; uint2 u; } z;
        z.hh[0] = (f16)pv[nt][0]; z.hh[1] = (f16)pv[nt][1];
        z.hh[2] = (f16)pv[nt][2]; z.hh[3] = (f16)pv[nt][3];
        *reinterpret_cast<uint2*>(&p_lds[wv][ql][nt * 16 + g * 4]) = z.u;
      }
      f16x8 pf[2];
      pf[0] = *reinterpret_cast<const f16x8*>(&p_lds[wv][ql][g * 8]);
      pf[1] = *reinterpret_cast<const f16x8*>(&p_lds[wv][ql][32 + g * 8]);

      // O^T += V^T P^T
      __builtin_amdgcn_s_setprio(1);
#pragma unroll
      for (int nt = 0; nt < 4; nt++) {
        o_acc[qs][nt] = MFMA16(vf[nt][0], pf[0], o_acc[qs][nt]);
        o_acc[qs][nt] = MFMA16(vf[nt][1], pf[1], o_acc[qs][nt]);
      }
      __builtin_amdgcn_s_setprio(0);
    }

    __syncthreads();
    cur ^= 1;
  }

  // epilogue: cross-lane l reduction (once), then write both q-groups
#pragma unroll
  for (int qs = 0; qs < 2; qs++) {
    const int qg = qs ? qg1 : qg0;
    float lt = l_r[qs];
    lt += __shfl_xor(lt, 16, 64);
    lt += __shfl_xor(lt, 32, 64);
    float rl = 1.0f / lt;
    float* op = out + ((size_t)(b * Sq + qg)) * (Hq * DHq) + h * DHq;
#pragma unroll
    for (int nt = 0; nt < 4; nt++) {
      float4 st = { o_acc[qs][nt][0] * rl, o_acc[qs][nt][1] * rl,
                    o_acc[qs][nt][2] * rl, o_acc[qs][nt][3] * rl };
      *reinterpret_cast<float4*>(op + nt * 16 + g * 4) = st;
    }
  }
}

extern "C" void kernel_launch(void* const* d_in, const int* in_sizes, int n_in,
                              void* d_out, int out_size, void* d_ws, size_t ws_size,
                              hipStream_t stream) {
  const float* x = (const float*)d_in[0];
  const float* Wq = (const float*)d_in[1];
  const float* Wk = (const float*)d_in[2];
  const float* Wv = (const float*)d_in[3];
  float* out = (float*)d_out;

  const size_t off_xb = 0;                    // 8192*768*2      = 12,582,912
  const size_t off_wt = 12582912;             // 2304*768*2      =  3,538,944
  const size_t off_q = 16121856;              // 96*1024*64*2    = 12,582,912
  const size_t off_k = 28704768;
  const size_t off_v = 41287680;
  const size_t need = 53870592;
  if (ws_size < need) return;

  char* ws = (char*)d_ws;
  f16* xh = (f16*)(ws + off_xb);
  f16* WT = (f16*)(ws + off_wt);
  f16* Qd = (f16*)(ws + off_q);
  f16* Kd = (f16*)(ws + off_k);
  f16* Vtd = (f16*)(ws + off_v);

  cvt_kernel<<<3504, 256, 0, stream>>>(x, Wq, Wk, Wv, xh, WT);
  proj_kernel<<<768, 256, 0, stream>>>(xh, WT, Qd, Kd, Vtd);
  attn_kernel<<<768, 256, 0, stream>>>(Qd, Kd, Vtd, out);
}